// Round 14
// baseline (375.596 us; speedup 1.0000x reference)
//
#include <hip/hip_runtime.h>
#include <hip/hip_bf16.h>

#define KD 6
#define DD 3
#define CO 32
#define CI 32
#define KC (KD * CO)   // 192
#define QP (KC / 2)    // 96 uints (bf16 pairs) per xg row
#define SCAN_T 256
#define SCAN_B 2048    // elements per scan block (256 threads x 8)

__device__ __forceinline__ uint pack_bf16(float a, float b) {
    uint lo = (uint)__bfloat16_as_ushort(__float2bfloat16(a));
    uint hi = (uint)__bfloat16_as_ushort(__float2bfloat16(b));
    return lo | (hi << 16);
}
__device__ __forceinline__ float bf_lo(uint u) { return __uint_as_float(u << 16); }
__device__ __forceinline__ float bf_hi(uint u) { return __uint_as_float(u & 0xffff0000u); }

// ---------------- kernel 1: xg = x @ g -> bf16 ws [N, 192] (unchanged) ----------------
__global__ __launch_bounds__(256, 4)
void xg_kernel(const float* __restrict__ x, const float* __restrict__ g,
               uint* __restrict__ xg, int N) {
    __shared__ float gs[CI * KC];  // 24 KiB
    for (int i = threadIdx.x; i < CI * KC; i += blockDim.x) gs[i] = g[i];
    __syncthreads();
    const int NP = (N + 1) >> 1;
    const int total = NP * 48;
    for (int idx = blockIdx.x * blockDim.x + threadIdx.x; idx < total;
         idx += gridDim.x * blockDim.x) {
        const int rp = idx / 48;
        const int t = idx - rp * 48;
        const int n0 = rp * 2;
        const int n1 = (n0 + 1 < N) ? (n0 + 1) : n0;
        const float* xr0 = x + (size_t)n0 * CI;
        const float* xr1 = x + (size_t)n1 * CI;
        float a00 = 0.f, a01 = 0.f, a02 = 0.f, a03 = 0.f;
        float a10 = 0.f, a11 = 0.f, a12 = 0.f, a13 = 0.f;
#pragma unroll 2
        for (int c = 0; c < CI; c += 4) {
            const float4 xv0 = *(const float4*)&xr0[c];
            const float4 xv1 = *(const float4*)&xr1[c];
            const float4 g0 = *(const float4*)&gs[(c + 0) * KC + 4 * t];
            const float4 g1 = *(const float4*)&gs[(c + 1) * KC + 4 * t];
            const float4 g2 = *(const float4*)&gs[(c + 2) * KC + 4 * t];
            const float4 g3 = *(const float4*)&gs[(c + 3) * KC + 4 * t];
            a00 = fmaf(xv0.x, g0.x, a00); a01 = fmaf(xv0.x, g0.y, a01);
            a02 = fmaf(xv0.x, g0.z, a02); a03 = fmaf(xv0.x, g0.w, a03);
            a10 = fmaf(xv1.x, g0.x, a10); a11 = fmaf(xv1.x, g0.y, a11);
            a12 = fmaf(xv1.x, g0.z, a12); a13 = fmaf(xv1.x, g0.w, a13);
            a00 = fmaf(xv0.y, g1.x, a00); a01 = fmaf(xv0.y, g1.y, a01);
            a02 = fmaf(xv0.y, g1.z, a02); a03 = fmaf(xv0.y, g1.w, a03);
            a10 = fmaf(xv1.y, g1.x, a10); a11 = fmaf(xv1.y, g1.y, a11);
            a12 = fmaf(xv1.y, g1.z, a12); a13 = fmaf(xv1.y, g1.w, a13);
            a00 = fmaf(xv0.z, g2.x, a00); a01 = fmaf(xv0.z, g2.y, a01);
            a02 = fmaf(xv0.z, g2.z, a02); a03 = fmaf(xv0.z, g2.w, a03);
            a10 = fmaf(xv1.z, g2.x, a10); a11 = fmaf(xv1.z, g2.y, a11);
            a12 = fmaf(xv1.z, g2.z, a12); a13 = fmaf(xv1.z, g2.w, a13);
            a00 = fmaf(xv0.w, g3.x, a00); a01 = fmaf(xv0.w, g3.y, a01);
            a02 = fmaf(xv0.w, g3.z, a02); a03 = fmaf(xv0.w, g3.w, a03);
            a10 = fmaf(xv1.w, g3.x, a10); a11 = fmaf(xv1.w, g3.y, a11);
            a12 = fmaf(xv1.w, g3.z, a12); a13 = fmaf(xv1.w, g3.w, a13);
        }
        uint2 pk0 = make_uint2(pack_bf16(a00, a01), pack_bf16(a02, a03));
        *(uint2*)(xg + (size_t)n0 * QP + 2 * t) = pk0;
        if (n0 + 1 < N) {
            uint2 pk1 = make_uint2(pack_bf16(a10, a11), pack_bf16(a12, a13));
            *(uint2*)(xg + (size_t)(n0 + 1) * QP + 2 * t) = pk1;
        }
    }
}

// ---------------- sort pass A: histogram of dst ----------------
__global__ void hist_kernel(const int* __restrict__ ei, int* __restrict__ hist, int E) {
    for (int e = blockIdx.x * blockDim.x + threadIdx.x; e < E;
         e += gridDim.x * blockDim.x)
        atomicAdd(&hist[ei[E + e]], 1);
}

// ---------------- sort pass B: scan (3 kernels) ----------------
__global__ void scanA_kernel(const int* __restrict__ hist, int* __restrict__ incl,
                             int* __restrict__ sums, int N) {
    __shared__ int lds[SCAN_T];
    const int t = threadIdx.x;
    const int base = blockIdx.x * SCAN_B + t * 8;
    int v[8]; int ts = 0;
#pragma unroll
    for (int j = 0; j < 8; ++j) { v[j] = (base + j < N) ? hist[base + j] : 0; ts += v[j]; }
    lds[t] = ts; __syncthreads();
    int acc = ts;
    for (int off = 1; off < SCAN_T; off <<= 1) {
        int add = (t >= off) ? lds[t - off] : 0;
        __syncthreads();
        acc += add; lds[t] = acc;
        __syncthreads();
    }
    int run = acc - ts;  // exclusive prefix of this thread within block
#pragma unroll
    for (int j = 0; j < 8; ++j) { run += v[j]; if (base + j < N) incl[base + j] = run; }
    if (t == SCAN_T - 1) sums[blockIdx.x] = acc;
}

__global__ void scanB_kernel(int* __restrict__ sums, int nb) {
    __shared__ int lds[SCAN_T];
    const int t = threadIdx.x;
    int v = (t < nb) ? sums[t] : 0;
    lds[t] = v; __syncthreads();
    int acc = v;
    for (int off = 1; off < SCAN_T; off <<= 1) {
        int add = (t >= off) ? lds[t - off] : 0;
        __syncthreads();
        acc += add; lds[t] = acc;
        __syncthreads();
    }
    if (t < nb) sums[t] = acc - v;  // exclusive
}

__global__ void scanC_kernel(const int* __restrict__ incl, const int* __restrict__ sums,
                             const int* __restrict__ hist, int* __restrict__ row_start,
                             int* __restrict__ cursor, int N) {
    const int i = blockIdx.x * blockDim.x + threadIdx.x;
    if (i == 0) row_start[0] = 0;
    if (i < N) {
        const int fin = incl[i] + sums[i / SCAN_B];
        row_start[i + 1] = fin;
        cursor[i] = fin - hist[i];
    }
}

// ---------------- sort pass C: scatter edges to dst bins (fused Gaussian) ----------
// sorted[pos] = {src, pack(w0,w1), pack(w2,w3), pack(w4,w5)}
__global__ void scatter_kernel(const int* __restrict__ ei, const float* __restrict__ pseudo,
                               const float* __restrict__ mu, const float* __restrict__ sigma,
                               int* __restrict__ cursor, uint4* __restrict__ sorted, int E) {
    float m[KD][DD], iv[KD][DD];
#pragma unroll
    for (int k = 0; k < KD; ++k)
#pragma unroll
        for (int d = 0; d < DD; ++d) {
            m[k][d] = mu[k * DD + d];
            float s = sigma[k * DD + d];
            iv[k][d] = -0.5f / (1e-15f + s * s);
        }
    for (int e = blockIdx.x * blockDim.x + threadIdx.x; e < E;
         e += gridDim.x * blockDim.x) {
        const int src = ei[e];
        const int dst = ei[E + e];
        const float p0 = pseudo[3 * e], p1 = pseudo[3 * e + 1], p2 = pseudo[3 * e + 2];
        float w[KD];
#pragma unroll
        for (int k = 0; k < KD; ++k) {
            float d0 = p0 - m[k][0], d1 = p1 - m[k][1], d2 = p2 - m[k][2];
            w[k] = __expf(d0 * d0 * iv[k][0] + d1 * d1 * iv[k][1] + d2 * d2 * iv[k][2]);
        }
        const int pos = atomicAdd(&cursor[dst], 1);
        sorted[pos] = make_uint4((uint)src, pack_bf16(w[0], w[1]),
                                 pack_bf16(w[2], w[3]), pack_bf16(w[4], w[5]));
    }
}

// ---------------- aggregate: 32 lanes per dst, zero atomics, streaming store ----------
// Lane l: pair p=l&15, kbase=l>>4; loads xg row uints l,l+32,l+64 (verified mapping).
__global__ void agg_kernel(const uint4* __restrict__ sorted, const uint* __restrict__ xg,
                           const int* __restrict__ row_start, float* __restrict__ out, int N) {
    const int l = threadIdx.x & 31;
    const int kbase = l >> 4;
    const int p = l & 15;
    const int d = (blockIdx.x * blockDim.x + threadIdx.x) >> 5;
    if (d >= N) return;
    const int s = row_start[d];
    const int t = row_start[d + 1];
    float s0 = 0.f, s1 = 0.f;
    for (int i = s; i < t; ++i) {
        const uint4 rec = sorted[i];
        const float wa = __uint_as_float((kbase ? (rec.y >> 16) : (rec.y & 0xffffu)) << 16);
        const float wb = __uint_as_float((kbase ? (rec.z >> 16) : (rec.z & 0xffffu)) << 16);
        const float wc = __uint_as_float((kbase ? (rec.w >> 16) : (rec.w & 0xffffu)) << 16);
        const uint* xr = xg + (size_t)rec.x * QP;
        const uint u0 = xr[l];
        const uint u1 = xr[l + 32];
        const uint u2 = xr[l + 64];
        s0 = fmaf(wa, bf_lo(u0), s0); s1 = fmaf(wa, bf_hi(u0), s1);
        s0 = fmaf(wb, bf_lo(u1), s0); s1 = fmaf(wb, bf_hi(u1), s1);
        s0 = fmaf(wc, bf_lo(u2), s0); s1 = fmaf(wc, bf_hi(u2), s1);
    }
    s0 += __shfl_xor(s0, 16);
    s1 += __shfl_xor(s1, 16);
    const float inv = 1.0f / fmaxf((float)(t - s), 1.0f);
    out[(size_t)d * CO + 2 * p + kbase] = (kbase ? s1 : s0) * inv;
}

// ---------------- epilogue: out += x@root + bias (mean already applied) ------------
__global__ void out_kernel(const float* __restrict__ x, const float* __restrict__ root,
                           const float* __restrict__ bias, float* __restrict__ out, int N) {
    __shared__ float rs[CI * CO];
    __shared__ float bs[CO];
    for (int i = threadIdx.x; i < CI * CO; i += blockDim.x) rs[i] = root[i];
    if (threadIdx.x < CO) bs[threadIdx.x] = bias[threadIdx.x];
    __syncthreads();
    const int total = N * 8;
    for (int idx = blockIdx.x * blockDim.x + threadIdx.x; idx < total;
         idx += gridDim.x * blockDim.x) {
        const int n = idx >> 3;
        const int t = idx & 7;
        const float* xr = x + (size_t)n * CI;
        float a0 = 0.f, a1 = 0.f, a2 = 0.f, a3 = 0.f;
#pragma unroll
        for (int c = 0; c < CI; ++c) {
            const float4 rv = *(const float4*)&rs[c * CO + 4 * t];
            float xc = xr[c];
            a0 = fmaf(xc, rv.x, a0);
            a1 = fmaf(xc, rv.y, a1);
            a2 = fmaf(xc, rv.z, a2);
            a3 = fmaf(xc, rv.w, a3);
        }
        float4 o = *(float4*)&out[(size_t)n * CO + 4 * t];
        const float4 bv = *(const float4*)&bs[4 * t];
        o.x = o.x + a0 + bv.x;
        o.y = o.y + a1 + bv.y;
        o.z = o.z + a2 + bv.z;
        o.w = o.w + a3 + bv.w;
        *(float4*)&out[(size_t)n * CO + 4 * t] = o;
    }
}

extern "C" void kernel_launch(void* const* d_in, const int* in_sizes, int n_in,
                              void* d_out, int out_size, void* d_ws, size_t ws_size,
                              hipStream_t stream) {
    const float* x      = (const float*)d_in[0];
    const int*   ei     = (const int*)d_in[1];
    const float* pseudo = (const float*)d_in[2];
    const float* g      = (const float*)d_in[3];
    const float* mu     = (const float*)d_in[4];
    const float* sigma  = (const float*)d_in[5];
    const float* root   = (const float*)d_in[6];
    const float* bias   = (const float*)d_in[7];
    float* out = (float*)d_out;

    const int N = in_sizes[0] / CI;
    const int E = in_sizes[1] / 2;

    // workspace layout (~84 MB)
    uint* xg       = (uint*)d_ws;                     // N*96 uints = 62.9 MB
    int*  hist     = (int*)(xg + (size_t)N * QP);     // N
    int*  incl     = hist + N;                        // N
    int*  row_start= incl + N;                        // N+1
    int*  cursor   = row_start + N + 1;               // N
    int*  sums     = cursor + N;                      // SCAN_T
    uint4* sorted  = (uint4*)(((uintptr_t)(sums + SCAN_T) + 15) & ~(uintptr_t)15);  // E*16B

    hipMemsetAsync(hist, 0, (size_t)N * sizeof(int), stream);

    const int blk = 256;

    xg_kernel<<<2048, blk, 0, stream>>>(x, g, xg, N);

    hist_kernel<<<2048, blk, 0, stream>>>(ei, hist, E);

    const int nb = (N + SCAN_B - 1) / SCAN_B;        // 81 for N=163842 (<=256 req'd)
    scanA_kernel<<<nb, SCAN_T, 0, stream>>>(hist, incl, sums, N);
    scanB_kernel<<<1, SCAN_T, 0, stream>>>(sums, nb);
    scanC_kernel<<<(N + blk - 1) / blk, blk, 0, stream>>>(incl, sums, hist, row_start,
                                                         cursor, N);

    scatter_kernel<<<2048, blk, 0, stream>>>(ei, pseudo, mu, sigma, cursor, sorted, E);

    agg_kernel<<<(N * 32 + blk - 1) / blk, blk, 0, stream>>>(sorted, xg, row_start, out, N);

    int grid3 = (N * 8 + blk - 1) / blk;
    if (grid3 > 4096) grid3 = 4096;
    out_kernel<<<grid3, blk, 0, stream>>>(x, root, bias, out, N);
}

// Round 15
// 362.943 us; speedup vs baseline: 1.0349x; 1.0349x over previous
//
#include <hip/hip_runtime.h>
#include <hip/hip_bf16.h>

#define KD 6
#define DD 3
#define CO 32
#define CI 32
#define KC (KD * CO)   // 192
#define QP (KC / 2)    // 96 uints (bf16 pairs) per xg row
#define SCAN_T 256
#define SCAN_B 2048

__device__ __forceinline__ uint pack_bf16(float a, float b) {
    uint lo = (uint)__bfloat16_as_ushort(__float2bfloat16(a));
    uint hi = (uint)__bfloat16_as_ushort(__float2bfloat16(b));
    return lo | (hi << 16);
}
__device__ __forceinline__ float bf_lo(uint u) { return __uint_as_float(u << 16); }
__device__ __forceinline__ float bf_hi(uint u) { return __uint_as_float(u & 0xffff0000u); }
__device__ __forceinline__ float selw(uint v, int kbase) {
    return __uint_as_float((kbase ? (v >> 16) : (v & 0xffffu)) << 16);
}

// ---------------- kernel 1: xg = x @ g -> bf16 ws [N, 192] ----------------
// 4 rows x 4 cols per thread: ds_read_b128 g-loads amortized over 4 rows
// (halves total LDS-pipe issue vs 2-row version). VGPR ~60 < 128 cap.
__global__ __launch_bounds__(256, 4)
void xg_kernel(const float* __restrict__ x, const float* __restrict__ g,
               uint* __restrict__ xg, int N) {
    __shared__ float gs[CI * KC];  // 24 KiB
    for (int i = threadIdx.x; i < CI * KC; i += blockDim.x) gs[i] = g[i];
    __syncthreads();
    const int NB = (N + 3) >> 2;
    const int total = NB * 48;
    for (int idx = blockIdx.x * blockDim.x + threadIdx.x; idx < total;
         idx += gridDim.x * blockDim.x) {
        const int b = idx / 48;
        const int t = idx - b * 48;   // cols 4t..4t+3
        const int n0 = b * 4;
        size_t ro0 = (size_t)n0 * CI;
        size_t ro1 = (size_t)((n0 + 1 < N) ? n0 + 1 : N - 1) * CI;
        size_t ro2 = (size_t)((n0 + 2 < N) ? n0 + 2 : N - 1) * CI;
        size_t ro3 = (size_t)((n0 + 3 < N) ? n0 + 3 : N - 1) * CI;
        float acc[4][4];
#pragma unroll
        for (int r = 0; r < 4; ++r) { acc[r][0] = acc[r][1] = acc[r][2] = acc[r][3] = 0.f; }
#pragma unroll 2
        for (int c = 0; c < CI; c += 4) {
            const float4 g0 = *(const float4*)&gs[(c + 0) * KC + 4 * t];
            const float4 g1 = *(const float4*)&gs[(c + 1) * KC + 4 * t];
            const float4 g2 = *(const float4*)&gs[(c + 2) * KC + 4 * t];
            const float4 g3 = *(const float4*)&gs[(c + 3) * KC + 4 * t];
            const float4 xv0 = *(const float4*)&x[ro0 + c];
            const float4 xv1 = *(const float4*)&x[ro1 + c];
            const float4 xv2 = *(const float4*)&x[ro2 + c];
            const float4 xv3 = *(const float4*)&x[ro3 + c];
#define ROWFMA(r, xv)                                                          \
            acc[r][0] = fmaf(xv.x, g0.x, acc[r][0]); acc[r][1] = fmaf(xv.x, g0.y, acc[r][1]); \
            acc[r][2] = fmaf(xv.x, g0.z, acc[r][2]); acc[r][3] = fmaf(xv.x, g0.w, acc[r][3]); \
            acc[r][0] = fmaf(xv.y, g1.x, acc[r][0]); acc[r][1] = fmaf(xv.y, g1.y, acc[r][1]); \
            acc[r][2] = fmaf(xv.y, g1.z, acc[r][2]); acc[r][3] = fmaf(xv.y, g1.w, acc[r][3]); \
            acc[r][0] = fmaf(xv.z, g2.x, acc[r][0]); acc[r][1] = fmaf(xv.z, g2.y, acc[r][1]); \
            acc[r][2] = fmaf(xv.z, g2.z, acc[r][2]); acc[r][3] = fmaf(xv.z, g2.w, acc[r][3]); \
            acc[r][0] = fmaf(xv.w, g3.x, acc[r][0]); acc[r][1] = fmaf(xv.w, g3.y, acc[r][1]); \
            acc[r][2] = fmaf(xv.w, g3.z, acc[r][2]); acc[r][3] = fmaf(xv.w, g3.w, acc[r][3]);
            ROWFMA(0, xv0) ROWFMA(1, xv1) ROWFMA(2, xv2) ROWFMA(3, xv3)
#undef ROWFMA
        }
#pragma unroll
        for (int r = 0; r < 4; ++r) {
            const int n = n0 + r;
            if (n < N) {
                uint2 pk = make_uint2(pack_bf16(acc[r][0], acc[r][1]),
                                      pack_bf16(acc[r][2], acc[r][3]));
                *(uint2*)(xg + (size_t)n * QP + 2 * t) = pk;
            }
        }
    }
}

// ---------------- sort pass A: histogram of dst ----------------
__global__ void hist_kernel(const int* __restrict__ ei, int* __restrict__ hist, int E) {
    for (int e = blockIdx.x * blockDim.x + threadIdx.x; e < E;
         e += gridDim.x * blockDim.x)
        atomicAdd(&hist[ei[E + e]], 1);
}

// ---------------- sort pass B: scan (3 kernels) ----------------
__global__ void scanA_kernel(const int* __restrict__ hist, int* __restrict__ incl,
                             int* __restrict__ sums, int N) {
    __shared__ int lds[SCAN_T];
    const int t = threadIdx.x;
    const int base = blockIdx.x * SCAN_B + t * 8;
    int v[8]; int ts = 0;
#pragma unroll
    for (int j = 0; j < 8; ++j) { v[j] = (base + j < N) ? hist[base + j] : 0; ts += v[j]; }
    lds[t] = ts; __syncthreads();
    int acc = ts;
    for (int off = 1; off < SCAN_T; off <<= 1) {
        int add = (t >= off) ? lds[t - off] : 0;
        __syncthreads();
        acc += add; lds[t] = acc;
        __syncthreads();
    }
    int run = acc - ts;
#pragma unroll
    for (int j = 0; j < 8; ++j) { run += v[j]; if (base + j < N) incl[base + j] = run; }
    if (t == SCAN_T - 1) sums[blockIdx.x] = acc;
}

__global__ void scanB_kernel(int* __restrict__ sums, int nb) {
    __shared__ int lds[SCAN_T];
    const int t = threadIdx.x;
    int v = (t < nb) ? sums[t] : 0;
    lds[t] = v; __syncthreads();
    int acc = v;
    for (int off = 1; off < SCAN_T; off <<= 1) {
        int add = (t >= off) ? lds[t - off] : 0;
        __syncthreads();
        acc += add; lds[t] = acc;
        __syncthreads();
    }
    if (t < nb) sums[t] = acc - v;
}

__global__ void scanC_kernel(const int* __restrict__ incl, const int* __restrict__ sums,
                             const int* __restrict__ hist, int* __restrict__ row_start,
                             int* __restrict__ cursor, int N) {
    const int i = blockIdx.x * blockDim.x + threadIdx.x;
    if (i == 0) row_start[0] = 0;
    if (i < N) {
        const int fin = incl[i] + sums[i / SCAN_B];
        row_start[i + 1] = fin;
        cursor[i] = fin - hist[i];
    }
}

// ---------------- sort pass C: scatter edges to dst bins (fused Gaussian) ----------
// 1 edge per thread (no grid-stride serial chain of atomic->store round trips).
__global__ void scatter_kernel(const int* __restrict__ ei, const float* __restrict__ pseudo,
                               const float* __restrict__ mu, const float* __restrict__ sigma,
                               int* __restrict__ cursor, uint4* __restrict__ sorted, int E) {
    const int e = blockIdx.x * blockDim.x + threadIdx.x;
    if (e >= E) return;
    float m[KD][DD], iv[KD][DD];
#pragma unroll
    for (int k = 0; k < KD; ++k)
#pragma unroll
        for (int d = 0; d < DD; ++d) {
            m[k][d] = mu[k * DD + d];
            float s = sigma[k * DD + d];
            iv[k][d] = -0.5f / (1e-15f + s * s);
        }
    const int src = ei[e];
    const int dst = ei[E + e];
    const float p0 = pseudo[3 * e], p1 = pseudo[3 * e + 1], p2 = pseudo[3 * e + 2];
    float w[KD];
#pragma unroll
    for (int k = 0; k < KD; ++k) {
        float d0 = p0 - m[k][0], d1 = p1 - m[k][1], d2 = p2 - m[k][2];
        w[k] = __expf(d0 * d0 * iv[k][0] + d1 * d1 * iv[k][1] + d2 * d2 * iv[k][2]);
    }
    const int pos = atomicAdd(&cursor[dst], 1);
    sorted[pos] = make_uint4((uint)src, pack_bf16(w[0], w[1]),
                             pack_bf16(w[2], w[3]), pack_bf16(w[4], w[5]));
}

// ---------------- aggregate + root + bias: one store per output element ----------
// 32 lanes/dst; lane l: pair p=l&15, kbase=l>>4; 2-edge software pipeline.
__global__ void agg_kernel(const uint4* __restrict__ sorted, const uint* __restrict__ xg,
                           const int* __restrict__ row_start, const float* __restrict__ x,
                           const float* __restrict__ root, const float* __restrict__ bias,
                           float* __restrict__ out, int N) {
    __shared__ float rs[CI * CO];  // 4 KiB
    __shared__ float bs[CO];
    for (int i = threadIdx.x; i < CI * CO; i += blockDim.x) rs[i] = root[i];
    if (threadIdx.x < CO) bs[threadIdx.x] = bias[threadIdx.x];
    __syncthreads();
    const int l = threadIdx.x & 31;
    const int kbase = l >> 4;
    const int p = l & 15;
    const int d = (blockIdx.x * blockDim.x + threadIdx.x) >> 5;
    if (d >= N) return;
    const int s = row_start[d];
    const int t = row_start[d + 1];
    float s0 = 0.f, s1 = 0.f;
    int i = s;
    for (; i + 1 < t; i += 2) {
        const uint4 ra = sorted[i];
        const uint4 rb = sorted[i + 1];
        const uint* xa = xg + (size_t)ra.x * QP;
        const uint* xb = xg + (size_t)rb.x * QP;
        const uint a0 = xa[l], a1 = xa[l + 32], a2 = xa[l + 64];
        const uint b0 = xb[l], b1 = xb[l + 32], b2 = xb[l + 64];
        float wa = selw(ra.y, kbase), wb = selw(ra.z, kbase), wc = selw(ra.w, kbase);
        s0 = fmaf(wa, bf_lo(a0), s0); s1 = fmaf(wa, bf_hi(a0), s1);
        s0 = fmaf(wb, bf_lo(a1), s0); s1 = fmaf(wb, bf_hi(a1), s1);
        s0 = fmaf(wc, bf_lo(a2), s0); s1 = fmaf(wc, bf_hi(a2), s1);
        wa = selw(rb.y, kbase); wb = selw(rb.z, kbase); wc = selw(rb.w, kbase);
        s0 = fmaf(wa, bf_lo(b0), s0); s1 = fmaf(wa, bf_hi(b0), s1);
        s0 = fmaf(wb, bf_lo(b1), s0); s1 = fmaf(wb, bf_hi(b1), s1);
        s0 = fmaf(wc, bf_lo(b2), s0); s1 = fmaf(wc, bf_hi(b2), s1);
    }
    if (i < t) {
        const uint4 ra = sorted[i];
        const uint* xa = xg + (size_t)ra.x * QP;
        const uint a0 = xa[l], a1 = xa[l + 32], a2 = xa[l + 64];
        const float wa = selw(ra.y, kbase), wb = selw(ra.z, kbase), wc = selw(ra.w, kbase);
        s0 = fmaf(wa, bf_lo(a0), s0); s1 = fmaf(wa, bf_hi(a0), s1);
        s0 = fmaf(wb, bf_lo(a1), s0); s1 = fmaf(wb, bf_hi(a1), s1);
        s0 = fmaf(wc, bf_lo(a2), s0); s1 = fmaf(wc, bf_hi(a2), s1);
    }
    s0 += __shfl_xor(s0, 16);
    s1 += __shfl_xor(s1, 16);
    const float inv = 1.0f / fmaxf((float)(t - s), 1.0f);
    const int ch = 2 * p + kbase;
    const float* xr = x + (size_t)d * CI;
    float acc = 0.f;
#pragma unroll
    for (int c = 0; c < CI; ++c) acc = fmaf(xr[c], rs[c * CO + ch], acc);
    out[(size_t)d * CO + ch] = (kbase ? s1 : s0) * inv + acc + bs[ch];
}

extern "C" void kernel_launch(void* const* d_in, const int* in_sizes, int n_in,
                              void* d_out, int out_size, void* d_ws, size_t ws_size,
                              hipStream_t stream) {
    const float* x      = (const float*)d_in[0];
    const int*   ei     = (const int*)d_in[1];
    const float* pseudo = (const float*)d_in[2];
    const float* g      = (const float*)d_in[3];
    const float* mu     = (const float*)d_in[4];
    const float* sigma  = (const float*)d_in[5];
    const float* root   = (const float*)d_in[6];
    const float* bias   = (const float*)d_in[7];
    float* out = (float*)d_out;

    const int N = in_sizes[0] / CI;
    const int E = in_sizes[1] / 2;

    uint* xg       = (uint*)d_ws;                     // N*96 uints = 62.9 MB
    int*  hist     = (int*)(xg + (size_t)N * QP);     // N
    int*  incl     = hist + N;                        // N
    int*  row_start= incl + N;                        // N+1
    int*  cursor   = row_start + N + 1;               // N
    int*  sums     = cursor + N;                      // SCAN_T
    uint4* sorted  = (uint4*)(((uintptr_t)(sums + SCAN_T) + 15) & ~(uintptr_t)15);  // E*16B

    hipMemsetAsync(hist, 0, (size_t)N * sizeof(int), stream);

    const int blk = 256;

    const int xg_total = ((N + 3) >> 2) * 48;
    xg_kernel<<<(xg_total + blk - 1) / blk, blk, 0, stream>>>(x, g, xg, N);

    hist_kernel<<<2048, blk, 0, stream>>>(ei, hist, E);

    const int nb = (N + SCAN_B - 1) / SCAN_B;
    scanA_kernel<<<nb, SCAN_T, 0, stream>>>(hist, incl, sums, N);
    scanB_kernel<<<1, SCAN_T, 0, stream>>>(sums, nb);
    scanC_kernel<<<(N + blk - 1) / blk, blk, 0, stream>>>(incl, sums, hist, row_start,
                                                         cursor, N);

    scatter_kernel<<<(E + blk - 1) / blk, blk, 0, stream>>>(ei, pseudo, mu, sigma,
                                                            cursor, sorted, E);

    agg_kernel<<<(N * 32 + blk - 1) / blk, blk, 0, stream>>>(sorted, xg, row_start,
                                                             x, root, bias, out, N);
}

// Round 16
// 353.634 us; speedup vs baseline: 1.0621x; 1.0263x over previous
//
#include <hip/hip_runtime.h>
#include <hip/hip_bf16.h>

#define KD 6
#define DD 3
#define CO 32
#define CI 32
#define KC (KD * CO)   // 192
#define QP (KC / 2)    // 96 uints (bf16 pairs) per xg row
#define SCAN_T 256
#define SCAN_B 2048

__device__ __forceinline__ uint pack_bf16(float a, float b) {
    uint lo = (uint)__bfloat16_as_ushort(__float2bfloat16(a));
    uint hi = (uint)__bfloat16_as_ushort(__float2bfloat16(b));
    return lo | (hi << 16);
}
__device__ __forceinline__ float bf_lo(uint u) { return __uint_as_float(u << 16); }
__device__ __forceinline__ float bf_hi(uint u) { return __uint_as_float(u & 0xffff0000u); }
__device__ __forceinline__ float selw(uint v, int kbase) {
    return __uint_as_float((kbase ? (v >> 16) : (v & 0xffffu)) << 16);
}

// ---------------- sort pass A: histogram of dst ----------------
__global__ void hist_kernel(const int* __restrict__ ei, int* __restrict__ hist, int E) {
    for (int e = blockIdx.x * blockDim.x + threadIdx.x; e < E;
         e += gridDim.x * blockDim.x)
        atomicAdd(&hist[ei[E + e]], 1);
}

// ---------------- sort pass B: scan (3 kernels) ----------------
__global__ void scanA_kernel(const int* __restrict__ hist, int* __restrict__ incl,
                             int* __restrict__ sums, int N) {
    __shared__ int lds[SCAN_T];
    const int t = threadIdx.x;
    const int base = blockIdx.x * SCAN_B + t * 8;
    int v[8]; int ts = 0;
#pragma unroll
    for (int j = 0; j < 8; ++j) { v[j] = (base + j < N) ? hist[base + j] : 0; ts += v[j]; }
    lds[t] = ts; __syncthreads();
    int acc = ts;
    for (int off = 1; off < SCAN_T; off <<= 1) {
        int add = (t >= off) ? lds[t - off] : 0;
        __syncthreads();
        acc += add; lds[t] = acc;
        __syncthreads();
    }
    int run = acc - ts;
#pragma unroll
    for (int j = 0; j < 8; ++j) { run += v[j]; if (base + j < N) incl[base + j] = run; }
    if (t == SCAN_T - 1) sums[blockIdx.x] = acc;
}

__global__ void scanB_kernel(int* __restrict__ sums, int nb) {
    __shared__ int lds[SCAN_T];
    const int t = threadIdx.x;
    int v = (t < nb) ? sums[t] : 0;
    lds[t] = v; __syncthreads();
    int acc = v;
    for (int off = 1; off < SCAN_T; off <<= 1) {
        int add = (t >= off) ? lds[t - off] : 0;
        __syncthreads();
        acc += add; lds[t] = acc;
        __syncthreads();
    }
    if (t < nb) sums[t] = acc - v;
}

__global__ void scanC_kernel(const int* __restrict__ incl, const int* __restrict__ sums,
                             const int* __restrict__ hist, int* __restrict__ row_start,
                             int* __restrict__ cursor, int N) {
    const int i = blockIdx.x * blockDim.x + threadIdx.x;
    if (i == 0) row_start[0] = 0;
    if (i < N) {
        const int fin = incl[i] + sums[i / SCAN_B];
        row_start[i + 1] = fin;
        cursor[i] = fin - hist[i];
    }
}

// ---------------- FUSED: scatter (blocks 0..SCB) || xg (remaining blocks) ----------
// Independent inputs/outputs; scatter is atomic/sector-write bound (VALU 6%),
// xg is LDS/VALU bound -> co-scheduled waves overlap (m114: time ~ max not sum).
__global__ __launch_bounds__(256, 4)
void scatter_xg_kernel(const int* __restrict__ ei, const float* __restrict__ pseudo,
                       const float* __restrict__ mu, const float* __restrict__ sigma,
                       int* __restrict__ cursor, uint4* __restrict__ sorted, int E,
                       const float* __restrict__ x, const float* __restrict__ g,
                       uint* __restrict__ xg, int N, int scatter_blocks) {
    __shared__ float gs[CI * KC];  // 24 KiB (xg role only)
    if (blockIdx.x < (uint)scatter_blocks) {
        // ---- scatter role: 1 edge per thread ----
        const int e = blockIdx.x * blockDim.x + threadIdx.x;
        if (e >= E) return;
        float m[KD][DD], iv[KD][DD];
#pragma unroll
        for (int k = 0; k < KD; ++k)
#pragma unroll
            for (int d = 0; d < DD; ++d) {
                m[k][d] = mu[k * DD + d];
                float s = sigma[k * DD + d];
                iv[k][d] = -0.5f / (1e-15f + s * s);
            }
        const int src = ei[e];
        const int dst = ei[E + e];
        const float p0 = pseudo[3 * e], p1 = pseudo[3 * e + 1], p2 = pseudo[3 * e + 2];
        float w[KD];
#pragma unroll
        for (int k = 0; k < KD; ++k) {
            float d0 = p0 - m[k][0], d1 = p1 - m[k][1], d2 = p2 - m[k][2];
            w[k] = __expf(d0 * d0 * iv[k][0] + d1 * d1 * iv[k][1] + d2 * d2 * iv[k][2]);
        }
        const int pos = atomicAdd(&cursor[dst], 1);
        sorted[pos] = make_uint4((uint)src, pack_bf16(w[0], w[1]),
                                 pack_bf16(w[2], w[3]), pack_bf16(w[4], w[5]));
        return;
    }
    // ---- xg role: 4 rows x 4 cols per thread ----
    for (int i = threadIdx.x; i < CI * KC; i += blockDim.x) gs[i] = g[i];
    __syncthreads();
    const int NB = (N + 3) >> 2;
    const int total = NB * 48;
    const int idx = (blockIdx.x - scatter_blocks) * blockDim.x + threadIdx.x;
    if (idx >= total) return;
    const int b = idx / 48;
    const int t = idx - b * 48;   // cols 4t..4t+3
    const int n0 = b * 4;
    size_t ro0 = (size_t)n0 * CI;
    size_t ro1 = (size_t)((n0 + 1 < N) ? n0 + 1 : N - 1) * CI;
    size_t ro2 = (size_t)((n0 + 2 < N) ? n0 + 2 : N - 1) * CI;
    size_t ro3 = (size_t)((n0 + 3 < N) ? n0 + 3 : N - 1) * CI;
    float acc[4][4];
#pragma unroll
    for (int r = 0; r < 4; ++r) { acc[r][0] = acc[r][1] = acc[r][2] = acc[r][3] = 0.f; }
#pragma unroll 2
    for (int c = 0; c < CI; c += 4) {
        const float4 g0 = *(const float4*)&gs[(c + 0) * KC + 4 * t];
        const float4 g1 = *(const float4*)&gs[(c + 1) * KC + 4 * t];
        const float4 g2 = *(const float4*)&gs[(c + 2) * KC + 4 * t];
        const float4 g3 = *(const float4*)&gs[(c + 3) * KC + 4 * t];
        const float4 xv0 = *(const float4*)&x[ro0 + c];
        const float4 xv1 = *(const float4*)&x[ro1 + c];
        const float4 xv2 = *(const float4*)&x[ro2 + c];
        const float4 xv3 = *(const float4*)&x[ro3 + c];
#define ROWFMA(r, xv)                                                          \
        acc[r][0] = fmaf(xv.x, g0.x, acc[r][0]); acc[r][1] = fmaf(xv.x, g0.y, acc[r][1]); \
        acc[r][2] = fmaf(xv.x, g0.z, acc[r][2]); acc[r][3] = fmaf(xv.x, g0.w, acc[r][3]); \
        acc[r][0] = fmaf(xv.y, g1.x, acc[r][0]); acc[r][1] = fmaf(xv.y, g1.y, acc[r][1]); \
        acc[r][2] = fmaf(xv.y, g1.z, acc[r][2]); acc[r][3] = fmaf(xv.y, g1.w, acc[r][3]); \
        acc[r][0] = fmaf(xv.z, g2.x, acc[r][0]); acc[r][1] = fmaf(xv.z, g2.y, acc[r][1]); \
        acc[r][2] = fmaf(xv.z, g2.z, acc[r][2]); acc[r][3] = fmaf(xv.z, g2.w, acc[r][3]); \
        acc[r][0] = fmaf(xv.w, g3.x, acc[r][0]); acc[r][1] = fmaf(xv.w, g3.y, acc[r][1]); \
        acc[r][2] = fmaf(xv.w, g3.z, acc[r][2]); acc[r][3] = fmaf(xv.w, g3.w, acc[r][3]);
        ROWFMA(0, xv0) ROWFMA(1, xv1) ROWFMA(2, xv2) ROWFMA(3, xv3)
#undef ROWFMA
    }
#pragma unroll
    for (int r = 0; r < 4; ++r) {
        const int n = n0 + r;
        if (n < N) {
            uint2 pk = make_uint2(pack_bf16(acc[r][0], acc[r][1]),
                                  pack_bf16(acc[r][2], acc[r][3]));
            *(uint2*)(xg + (size_t)n * QP + 2 * t) = pk;
        }
    }
}

// ---------------- aggregate + root + bias: one store per output element ----------
__global__ void agg_kernel(const uint4* __restrict__ sorted, const uint* __restrict__ xg,
                           const int* __restrict__ row_start, const float* __restrict__ x,
                           const float* __restrict__ root, const float* __restrict__ bias,
                           float* __restrict__ out, int N) {
    __shared__ float rs[CI * CO];  // 4 KiB
    __shared__ float bs[CO];
    for (int i = threadIdx.x; i < CI * CO; i += blockDim.x) rs[i] = root[i];
    if (threadIdx.x < CO) bs[threadIdx.x] = bias[threadIdx.x];
    __syncthreads();
    const int l = threadIdx.x & 31;
    const int kbase = l >> 4;
    const int p = l & 15;
    const int d = (blockIdx.x * blockDim.x + threadIdx.x) >> 5;
    if (d >= N) return;
    const int s = row_start[d];
    const int t = row_start[d + 1];
    float s0 = 0.f, s1 = 0.f;
    int i = s;
    for (; i + 1 < t; i += 2) {
        const uint4 ra = sorted[i];
        const uint4 rb = sorted[i + 1];
        const uint* xa = xg + (size_t)ra.x * QP;
        const uint* xb = xg + (size_t)rb.x * QP;
        const uint a0 = xa[l], a1 = xa[l + 32], a2 = xa[l + 64];
        const uint b0 = xb[l], b1 = xb[l + 32], b2 = xb[l + 64];
        float wa = selw(ra.y, kbase), wb = selw(ra.z, kbase), wc = selw(ra.w, kbase);
        s0 = fmaf(wa, bf_lo(a0), s0); s1 = fmaf(wa, bf_hi(a0), s1);
        s0 = fmaf(wb, bf_lo(a1), s0); s1 = fmaf(wb, bf_hi(a1), s1);
        s0 = fmaf(wc, bf_lo(a2), s0); s1 = fmaf(wc, bf_hi(a2), s1);
        wa = selw(rb.y, kbase); wb = selw(rb.z, kbase); wc = selw(rb.w, kbase);
        s0 = fmaf(wa, bf_lo(b0), s0); s1 = fmaf(wa, bf_hi(b0), s1);
        s0 = fmaf(wb, bf_lo(b1), s0); s1 = fmaf(wb, bf_hi(b1), s1);
        s0 = fmaf(wc, bf_lo(b2), s0); s1 = fmaf(wc, bf_hi(b2), s1);
    }
    if (i < t) {
        const uint4 ra = sorted[i];
        const uint* xa = xg + (size_t)ra.x * QP;
        const uint a0 = xa[l], a1 = xa[l + 32], a2 = xa[l + 64];
        const float wa = selw(ra.y, kbase), wb = selw(ra.z, kbase), wc = selw(ra.w, kbase);
        s0 = fmaf(wa, bf_lo(a0), s0); s1 = fmaf(wa, bf_hi(a0), s1);
        s0 = fmaf(wb, bf_lo(a1), s0); s1 = fmaf(wb, bf_hi(a1), s1);
        s0 = fmaf(wc, bf_lo(a2), s0); s1 = fmaf(wc, bf_hi(a2), s1);
    }
    s0 += __shfl_xor(s0, 16);
    s1 += __shfl_xor(s1, 16);
    const float inv = 1.0f / fmaxf((float)(t - s), 1.0f);
    const int ch = 2 * p + kbase;
    const float* xr = x + (size_t)d * CI;
    float acc = 0.f;
#pragma unroll
    for (int c = 0; c < CI; ++c) acc = fmaf(xr[c], rs[c * CO + ch], acc);
    out[(size_t)d * CO + ch] = (kbase ? s1 : s0) * inv + acc + bs[ch];
}

extern "C" void kernel_launch(void* const* d_in, const int* in_sizes, int n_in,
                              void* d_out, int out_size, void* d_ws, size_t ws_size,
                              hipStream_t stream) {
    const float* x      = (const float*)d_in[0];
    const int*   ei     = (const int*)d_in[1];
    const float* pseudo = (const float*)d_in[2];
    const float* g      = (const float*)d_in[3];
    const float* mu     = (const float*)d_in[4];
    const float* sigma  = (const float*)d_in[5];
    const float* root   = (const float*)d_in[6];
    const float* bias   = (const float*)d_in[7];
    float* out = (float*)d_out;

    const int N = in_sizes[0] / CI;
    const int E = in_sizes[1] / 2;

    uint* xg       = (uint*)d_ws;                     // N*96 uints = 62.9 MB
    int*  hist     = (int*)(xg + (size_t)N * QP);     // N
    int*  incl     = hist + N;                        // N
    int*  row_start= incl + N;                        // N+1
    int*  cursor   = row_start + N + 1;               // N
    int*  sums     = cursor + N;                      // SCAN_T
    uint4* sorted  = (uint4*)(((uintptr_t)(sums + SCAN_T) + 15) & ~(uintptr_t)15);  // E*16B

    hipMemsetAsync(hist, 0, (size_t)N * sizeof(int), stream);

    const int blk = 256;

    hist_kernel<<<2048, blk, 0, stream>>>(ei, hist, E);

    const int nb = (N + SCAN_B - 1) / SCAN_B;
    scanA_kernel<<<nb, SCAN_T, 0, stream>>>(hist, incl, sums, N);
    scanB_kernel<<<1, SCAN_T, 0, stream>>>(sums, nb);
    scanC_kernel<<<(N + blk - 1) / blk, blk, 0, stream>>>(incl, sums, hist, row_start,
                                                         cursor, N);

    const int scatter_blocks = (E + blk - 1) / blk;              // 4481
    const int xg_blocks = ((((N + 3) >> 2) * 48) + blk - 1) / blk; // 7681
    scatter_xg_kernel<<<scatter_blocks + xg_blocks, blk, 0, stream>>>(
        ei, pseudo, mu, sigma, cursor, sorted, E, x, g, xg, N, scatter_blocks);

    agg_kernel<<<(N * 32 + blk - 1) / blk, blk, 0, stream>>>(sorted, xg, row_start,
                                                             x, root, bias, out, N);
}